// Round 1
// baseline (232.425 us; speedup 1.0000x reference)
//
#include <hip/hip_runtime.h>

typedef short bf16x8 __attribute__((ext_vector_type(8)));
typedef float f32x4 __attribute__((ext_vector_type(4)));
typedef unsigned short u16;

// ---------- helpers ----------

__device__ __forceinline__ u16 f2b(float f) {
  unsigned int u = __float_as_uint(f);
  u += 0x7fffu + ((u >> 16) & 1u);   // RNE
  return (u16)(u >> 16);
}

__device__ __forceinline__ void gload16(const void* g, void* l) {
  __builtin_amdgcn_global_load_lds(
      (const __attribute__((address_space(1))) void*)g,
      (__attribute__((address_space(3))) void*)l, 16, 0, 0);
}

// ---------- 128x128 NT GEMM tile body ----------
// A: [M rows][lda] bf16 row-major, B: [N rows][ldb] bf16 row-major (i.e. B^T),
// D[m][n] = sum_k A[i0+m][k]*B[j0+n][k] over k in [kt0*32, kt1*32).
// 256 threads = 4 waves, each wave owns a 64x64 quadrant (4x4 16x16 frags).
__device__ __forceinline__ void gemm_tile(
    const u16* __restrict__ A, int lda,
    const u16* __restrict__ B, int ldb,
    int i0, int j0, int kt0, int kt1,
    u16* lA, u16* lB, f32x4 acc[4][4])
{
  const int t = threadIdx.x;
  const int lane = t & 63;
  const int wrow = t >> 7;
  const int wcol = (t >> 6) & 1;
  const int rr = lane & 15, kg = lane >> 4;
  const int srow = t >> 2;          // staging row 0..63
  const int scol = (t & 3) * 8;     // staging col (elements)
  const u16* gA = A + (size_t)(i0 + srow) * lda + scol;
  const u16* gB = B + (size_t)(j0 + srow) * ldb + scol;
  char* dA = (char*)lA + t * 16;
  char* dB = (char*)lB + t * 16;

  for (int kt = kt0; kt < kt1; ++kt) {
    const int kk = kt * 32;
    gload16(gA + kk, dA);
    gload16(gA + kk + (size_t)64 * lda, dA + 4096);
    gload16(gB + kk, dB);
    gload16(gB + kk + (size_t)64 * ldb, dB + 4096);
    __syncthreads();   // drains vmcnt before barrier (compiler-inserted)
    bf16x8 af[4], bf[4];
#pragma unroll
    for (int mi = 0; mi < 4; ++mi)
      af[mi] = *(const bf16x8*)(lA + (wrow * 64 + mi * 16 + rr) * 32 + kg * 8);
#pragma unroll
    for (int ni = 0; ni < 4; ++ni)
      bf[ni] = *(const bf16x8*)(lB + (wcol * 64 + ni * 16 + rr) * 32 + kg * 8);
#pragma unroll
    for (int mi = 0; mi < 4; ++mi)
#pragma unroll
      for (int ni = 0; ni < 4; ++ni)
        acc[mi][ni] = __builtin_amdgcn_mfma_f32_16x16x32_bf16(
            af[mi], bf[ni], acc[mi][ni], 0, 0, 0);
    __syncthreads();
  }
}

// ---------- kernel 0: fp32 -> bf16 conversion (x and stacked W) ----------
// xb: 8388608 elems; Wb: rows [Wq;Wk;Wv] = 3072x1024 = 3145728 elems.
__global__ __launch_bounds__(256) void k_convert(
    const float* __restrict__ x, const float* __restrict__ Wq,
    const float* __restrict__ Wk, const float* __restrict__ Wv,
    u16* __restrict__ xb, u16* __restrict__ Wb)
{
  const size_t NX = 8388608;
  size_t base = ((size_t)blockIdx.x * 256 + threadIdx.x) * 4;
  float4 v;
  u16* dst;
  if (base < NX) {
    v = *(const float4*)(x + base);
    dst = xb + base;
  } else {
    size_t wb = base - NX;
    int sel = (int)(wb >> 20);
    const float* W = (sel == 0) ? Wq : ((sel == 1) ? Wk : Wv);
    v = *(const float4*)(W + (wb & 1048575));
    dst = Wb + wb;
  }
  dst[0] = f2b(v.x); dst[1] = f2b(v.y); dst[2] = f2b(v.z); dst[3] = f2b(v.w);
}

// ---------- kernel 1: QKV projection GEMM ----------
// C[8192][3072] = xb @ Wb^T.  Epilogue:
//   n in [0,1024):    Qb  = c + bq[d]
//   n in [1024,2048): Kpb = c + bk[d] + x + P          (K' = k + pos)
//   n in [2048,3072): Vtb[b][d][s] = c + bv[d]         (pre-transposed V)
__global__ __launch_bounds__(256) void k_qkv(
    const u16* __restrict__ xb, const u16* __restrict__ Wb,
    const float* __restrict__ bq, const float* __restrict__ bk,
    const float* __restrict__ bv, const float* __restrict__ x,
    const float* __restrict__ P,
    u16* __restrict__ Qb, u16* __restrict__ Kpb, u16* __restrict__ Vtb)
{
  __shared__ __align__(16) u16 lA[4096];
  __shared__ __align__(16) u16 lB[4096];
  const int bx = blockIdx.x;
  const int bi = bx & 63, bj = bx >> 6;   // 64 M-tiles x 24 N-tiles
  const int i0 = bi * 128, j0 = bj * 128;
  f32x4 acc[4][4];
#pragma unroll
  for (int a = 0; a < 4; ++a)
#pragma unroll
    for (int b = 0; b < 4; ++b) acc[a][b] = (f32x4){0.f, 0.f, 0.f, 0.f};

  gemm_tile(xb, 1024, Wb, 1024, i0, j0, 0, 32, lA, lB, acc);

  const int t = threadIdx.x, lane = t & 63;
  const int wrow = t >> 7, wcol = (t >> 6) & 1;
  const int rr = lane & 15, kg = lane >> 4;
  const int sec = j0 >> 10;   // uniform per block
#pragma unroll
  for (int mi = 0; mi < 4; ++mi)
#pragma unroll
    for (int ni = 0; ni < 4; ++ni)
#pragma unroll
      for (int r = 0; r < 4; ++r) {
        int m = i0 + wrow * 64 + mi * 16 + kg * 4 + r;
        int n = j0 + wcol * 64 + ni * 16 + rr;
        int d = n & 1023;
        float v = acc[mi][ni][r];
        if (sec == 0) {
          v += bq[d];
          Qb[(size_t)m * 1024 + d] = f2b(v);
        } else if (sec == 1) {
          int s = m & 2047;
          v += bk[d] + x[(size_t)m * 1024 + d] + P[(size_t)s * 1024 + d];
          Kpb[(size_t)m * 1024 + d] = f2b(v);
        } else {
          int b = m >> 11, s = m & 2047;
          v += bv[d];
          Vtb[((size_t)b * 1024 + d) * 2048 + s] = f2b(v);
        }
      }
}

// ---------- kernel 2: scores GEMM (lower-triangular blocks only) ----------
// Sf[b][i][j] = (Q[b,i,:] . K'[b,j,:]) / 32, fp32
__global__ __launch_bounds__(256) void k_scores(
    const u16* __restrict__ Qb, const u16* __restrict__ Kpb,
    float* __restrict__ Sf)
{
  __shared__ __align__(16) u16 lA[4096];
  __shared__ __align__(16) u16 lB[4096];
  const int bx = blockIdx.x;
  const int b = bx / 136;
  const int tt = bx - b * 136;
  int bi = (int)((sqrtf(8.f * tt + 1.f) - 1.f) * 0.5f);
  while ((bi + 1) * (bi + 2) / 2 <= tt) ++bi;
  while (bi * (bi + 1) / 2 > tt) --bi;
  const int bj = tt - bi * (bi + 1) / 2;
  const int i0 = bi * 128, j0 = bj * 128;
  const u16* A = Qb + (size_t)b * 2048 * 1024;
  const u16* B = Kpb + (size_t)b * 2048 * 1024;

  f32x4 acc[4][4];
#pragma unroll
  for (int a = 0; a < 4; ++a)
#pragma unroll
    for (int c = 0; c < 4; ++c) acc[a][c] = (f32x4){0.f, 0.f, 0.f, 0.f};

  gemm_tile(A, 1024, B, 1024, i0, j0, 0, 32, lA, lB, acc);

  const int t = threadIdx.x, lane = t & 63;
  const int wrow = t >> 7, wcol = (t >> 6) & 1;
  const int rr = lane & 15, kg = lane >> 4;
  float* Sb = Sf + (size_t)b * 2048 * 2048;
#pragma unroll
  for (int mi = 0; mi < 4; ++mi)
#pragma unroll
    for (int ni = 0; ni < 4; ++ni)
#pragma unroll
      for (int r = 0; r < 4; ++r) {
        int m = i0 + wrow * 64 + mi * 16 + kg * 4 + r;
        int n = j0 + wcol * 64 + ni * 16 + rr;
        Sb[(size_t)m * 2048 + n] = acc[mi][ni][r] * 0.03125f;
      }
}

// ---------- kernel 3: row softmax (causal), fp32 scores -> bf16 probs ----------
__global__ __launch_bounds__(256) void k_softmax(
    const float* __restrict__ Sf, u16* __restrict__ Pb)
{
  __shared__ float red[4];
  const int row = blockIdx.x;          // b*2048 + i
  const int i = row & 2047;
  const int L = i + 1;
  const float* s = Sf + (size_t)row * 2048;
  u16* p = Pb + (size_t)row * 2048;
  const int t = threadIdx.x;

  float m = -3.0e38f;
  for (int j = t; j < L; j += 256) m = fmaxf(m, s[j]);
#pragma unroll
  for (int off = 32; off >= 1; off >>= 1) m = fmaxf(m, __shfl_down(m, off, 64));
  if ((t & 63) == 0) red[t >> 6] = m;
  __syncthreads();
  m = fmaxf(fmaxf(red[0], red[1]), fmaxf(red[2], red[3]));
  __syncthreads();

  float sum = 0.f;
  for (int j = t; j < L; j += 256) sum += __expf(s[j] - m);
#pragma unroll
  for (int off = 32; off >= 1; off >>= 1) sum += __shfl_down(sum, off, 64);
  if ((t & 63) == 0) red[t >> 6] = sum;
  __syncthreads();
  sum = red[0] + red[1] + red[2] + red[3];
  const float inv = 1.f / sum;

  for (int j = t; j < 2048; j += 256) {
    float v = (j < L) ? __expf(s[j] - m) * inv : 0.f;
    p[j] = f2b(v);
  }
}

// ---------- kernel 4: out = P @ V  (uses pre-transposed Vtb) ----------
__global__ __launch_bounds__(256) void k_pv(
    const u16* __restrict__ Pb, const u16* __restrict__ Vtb,
    float* __restrict__ out)
{
  __shared__ __align__(16) u16 lA[4096];
  __shared__ __align__(16) u16 lB[4096];
  const int bx = blockIdx.x;
  const int b = bx >> 7;
  const int bi = (bx >> 3) & 15;
  const int bj = bx & 7;
  const int i0 = bi * 128, j0 = bj * 128;
  const u16* A = Pb + (size_t)b * 2048 * 2048;   // lda 2048 (k = key index)
  const u16* B = Vtb + (size_t)b * 1024 * 2048;  // ldb 2048 (rows = d)

  f32x4 acc[4][4];
#pragma unroll
  for (int a = 0; a < 4; ++a)
#pragma unroll
    for (int c = 0; c < 4; ++c) acc[a][c] = (f32x4){0.f, 0.f, 0.f, 0.f};

  // causal: probs are zero for j >= (bi+1)*128, so only (bi+1)*4 k-tiles
  gemm_tile(A, 2048, B, 2048, i0, j0, 0, (bi + 1) * 4, lA, lB, acc);

  const int t = threadIdx.x, lane = t & 63;
  const int wrow = t >> 7, wcol = (t >> 6) & 1;
  const int rr = lane & 15, kg = lane >> 4;
  float* ob = out + (size_t)b * 2048 * 1024;
#pragma unroll
  for (int mi = 0; mi < 4; ++mi)
#pragma unroll
    for (int ni = 0; ni < 4; ++ni)
#pragma unroll
      for (int r = 0; r < 4; ++r) {
        int m = i0 + wrow * 64 + mi * 16 + kg * 4 + r;
        int n = j0 + wcol * 64 + ni * 16 + rr;
        ob[(size_t)m * 1024 + n] = acc[mi][ni][r];
      }
}

// ---------- launch ----------
extern "C" void kernel_launch(void* const* d_in, const int* in_sizes, int n_in,
                              void* d_out, int out_size, void* d_ws, size_t ws_size,
                              hipStream_t stream) {
  const float* x  = (const float*)d_in[0];
  const float* Wq = (const float*)d_in[1];
  const float* bq = (const float*)d_in[2];
  const float* Wk = (const float*)d_in[3];
  const float* bk = (const float*)d_in[4];
  const float* Wv = (const float*)d_in[5];
  const float* bv = (const float*)d_in[6];
  const float* P  = (const float*)d_in[7];
  float* out = (float*)d_out;

  char* w = (char*)d_ws;
  u16*  xb  = (u16*)(w);                  // 16 MB
  u16*  Wb  = (u16*)(w + (16ull << 20));  //  6 MB
  u16*  Qb  = (u16*)(w + (22ull << 20));  // 16 MB
  u16*  Kpb = (u16*)(w + (38ull << 20));  // 16 MB
  u16*  Vtb = (u16*)(w + (54ull << 20));  // 16 MB
  float* Sf = (float*)(w + (70ull << 20)); // 64 MB
  u16*  Pb  = (u16*)(w + (134ull << 20)); // 32 MB  (total 166 MB)

  hipLaunchKernelGGL(k_convert, dim3(11264), dim3(256), 0, stream,
                     x, Wq, Wk, Wv, xb, Wb);
  hipLaunchKernelGGL(k_qkv, dim3(1536), dim3(256), 0, stream,
                     xb, Wb, bq, bk, bv, x, P, Qb, Kpb, Vtb);
  hipLaunchKernelGGL(k_scores, dim3(544), dim3(256), 0, stream,
                     Qb, Kpb, Sf);
  hipLaunchKernelGGL(k_softmax, dim3(8192), dim3(256), 0, stream,
                     Sf, Pb);
  hipLaunchKernelGGL(k_pv, dim3(512), dim3(256), 0, stream,
                     Pb, Vtb, out);
}

// Round 2
// 194.154 us; speedup vs baseline: 1.1971x; 1.1971x over previous
//
#include <hip/hip_runtime.h>

typedef short bf16x8 __attribute__((ext_vector_type(8)));
typedef float f32x4 __attribute__((ext_vector_type(4)));
typedef unsigned long long u64x2 __attribute__((ext_vector_type(2)));
typedef unsigned short u16;

// ---------- helpers ----------

__device__ __forceinline__ u16 f2b(float f) {
  unsigned int u = __float_as_uint(f);
  u += 0x7fffu + ((u >> 16) & 1u);   // RNE
  return (u16)(u >> 16);
}

__device__ __forceinline__ void gload16(const void* g, void* l) {
  __builtin_amdgcn_global_load_lds(
      (const __attribute__((address_space(1))) void*)g,
      (__attribute__((address_space(3))) void*)l, 16, 0, 0);
}

// ---------- 256x256 BK=64 8-wave NT GEMM ----------
// A: rows [i0,i0+256) x K, row-major lda. B: rows [j0,j0+256) x K, row-major ldb.
// D[m][n] = sum_k A[i0+m][k] * B[j0+n][k], k in [0, nk*64).
// 512 threads = 8 waves (2M x 4N); per-wave output 128x64 = acc[8][4] frags.
// LDS: 2 x (A 256x64 + B 256x64) bf16 = 128 KiB, XOR-swizzled (slot ^= row&7).

// Stage one 256x64 K-tile of A and B. LDS dest is linear (wave-uniform+lane*16);
// the swizzle is applied to the GLOBAL source column (rule 21 / m173 pattern).
__device__ __forceinline__ void stage_tile(
    const u16* __restrict__ gA, int lda, const u16* __restrict__ gB, int ldb,
    u16* bufA, u16* bufB)
{
  const int t = threadIdx.x;
  const int rb = t >> 3;                        // row 0..63 (+64/round)
  const int c16 = ((t & 7) ^ (rb & 7)) * 8;     // swizzled 16B slot (elems)
  const u16* pa = gA + (size_t)rb * lda + c16;
  const u16* pb = gB + (size_t)rb * ldb + c16;
  char* da = (char*)bufA + t * 16;
  char* db = (char*)bufB + t * 16;
#pragma unroll
  for (int rnd = 0; rnd < 4; ++rnd) {
    gload16(pa + (size_t)(rnd * 64) * lda, da + rnd * 8192);
    gload16(pb + (size_t)(rnd * 64) * ldb, db + rnd * 8192);
  }
}

__device__ __forceinline__ void compute_ktile(
    const u16* bufA, const u16* bufB,
    int wrow, int wcol, int rr, int laneOff, f32x4 acc[8][4])
{
  bf16x8 bfr[4][2];
#pragma unroll
  for (int ni = 0; ni < 4; ++ni) {
    const char* base = (const char*)bufB + (wcol * 64 + ni * 16 + rr) * 128;
    bfr[ni][0] = *(const bf16x8*)(base + laneOff);
    bfr[ni][1] = *(const bf16x8*)(base + (laneOff ^ 64));
  }
#pragma unroll
  for (int mi = 0; mi < 8; ++mi) {
    const char* base = (const char*)bufA + (wrow * 128 + mi * 16 + rr) * 128;
    bf16x8 a0 = *(const bf16x8*)(base + laneOff);
    bf16x8 a1 = *(const bf16x8*)(base + (laneOff ^ 64));
#pragma unroll
    for (int ni = 0; ni < 4; ++ni) {
      acc[mi][ni] = __builtin_amdgcn_mfma_f32_16x16x32_bf16(a0, bfr[ni][0], acc[mi][ni], 0, 0, 0);
      acc[mi][ni] = __builtin_amdgcn_mfma_f32_16x16x32_bf16(a1, bfr[ni][1], acc[mi][ni], 0, 0, 0);
    }
  }
}

__device__ __forceinline__ void gemm256(
    const u16* __restrict__ A, int lda, const u16* __restrict__ B, int ldb,
    int i0, int j0, int nk, u16* lds, f32x4 acc[8][4])
{
  u16* bufA0 = lds;
  u16* bufB0 = lds + 16384;
  u16* bufA1 = lds + 32768;
  u16* bufB1 = lds + 49152;
  const int t = threadIdx.x;
  const int lane = t & 63, wid = t >> 6;
  const int wrow = wid >> 2, wcol = wid & 3;
  const int rr = lane & 15, kg = lane >> 4;
  const int laneOff = (kg * 16) ^ ((rr & 7) << 4);
  const u16* Abase = A + (size_t)i0 * lda;
  const u16* Bbase = B + (size_t)j0 * ldb;

  stage_tile(Abase, lda, Bbase, ldb, bufA0, bufB0);
  if (nk > 1) {
    stage_tile(Abase + 64, lda, Bbase + 64, ldb, bufA1, bufB1);
    asm volatile("s_waitcnt vmcnt(8)" ::: "memory");
  } else {
    asm volatile("s_waitcnt vmcnt(0)" ::: "memory");
  }
  __builtin_amdgcn_sched_barrier(0);
  __builtin_amdgcn_s_barrier();
  __builtin_amdgcn_sched_barrier(0);

  for (int kt = 0; kt < nk; ++kt) {
    const u16* bA = (kt & 1) ? bufA1 : bufA0;
    const u16* bB = (kt & 1) ? bufB1 : bufB0;
    compute_ktile(bA, bB, wrow, wcol, rr, laneOff, acc);
    __builtin_amdgcn_sched_barrier(0);
    __builtin_amdgcn_s_barrier();          // all waves done reading buf[kt&1]
    __builtin_amdgcn_sched_barrier(0);
    if (kt + 2 < nk) {
      // restage the freed buffer with K-tile kt+2; keep 8 loads in flight
      u16* dA = (kt & 1) ? bufA1 : bufA0;
      u16* dB = (kt & 1) ? bufB1 : bufB0;
      stage_tile(Abase + (kt + 2) * 64, lda, Bbase + (kt + 2) * 64, ldb, dA, dB);
      asm volatile("s_waitcnt vmcnt(8)" ::: "memory");  // K-tile kt+1 landed
    } else {
      asm volatile("s_waitcnt vmcnt(0)" ::: "memory");
    }
    __builtin_amdgcn_sched_barrier(0);
    __builtin_amdgcn_s_barrier();          // buf[(kt+1)&1] published
    __builtin_amdgcn_sched_barrier(0);
  }
}

// ---------- kernel 0: fp32 -> bf16 conversion (x and stacked W) ----------
__global__ __launch_bounds__(256) void k_convert(
    const float* __restrict__ x, const float* __restrict__ Wq,
    const float* __restrict__ Wk, const float* __restrict__ Wv,
    u16* __restrict__ xb, u16* __restrict__ Wb)
{
  const size_t NX = 8388608;
  size_t base = ((size_t)blockIdx.x * 256 + threadIdx.x) * 4;
  float4 v;
  u16* dst;
  if (base < NX) {
    v = *(const float4*)(x + base);
    dst = xb + base;
  } else {
    size_t wb = base - NX;
    int sel = (int)(wb >> 20);
    const float* W = (sel == 0) ? Wq : ((sel == 1) ? Wk : Wv);
    v = *(const float4*)(W + (wb & 1048575));
    dst = Wb + wb;
  }
  dst[0] = f2b(v.x); dst[1] = f2b(v.y); dst[2] = f2b(v.z); dst[3] = f2b(v.w);
}

// ---------- kernel 1: QKV projection ----------
// C[8192][3072] = xb @ Wb^T.  bj 0-3 -> Q, 4-7 -> K' (=k+x+P), 8-11 -> V^T.
__global__ __launch_bounds__(512, 2) void k_qkv(
    const u16* __restrict__ xb, const u16* __restrict__ Wb,
    const float* __restrict__ bq, const float* __restrict__ bk,
    const float* __restrict__ bv, const float* __restrict__ x,
    const float* __restrict__ P,
    u16* __restrict__ Qb, u16* __restrict__ Kpb, u16* __restrict__ Vtb)
{
  extern __shared__ __align__(16) u16 lds[];
  const int bx = blockIdx.x;
  const int bi = bx & 31, bj = bx >> 5;   // 32 M-tiles x 12 N-tiles
  const int i0 = bi * 256, j0 = bj * 256;
  f32x4 acc[8][4];
#pragma unroll
  for (int a = 0; a < 8; ++a)
#pragma unroll
    for (int b = 0; b < 4; ++b) acc[a][b] = (f32x4){0.f, 0.f, 0.f, 0.f};

  gemm256(xb, 1024, Wb, 1024, i0, j0, 16, lds, acc);

  const int t = threadIdx.x, lane = t & 63, wid = t >> 6;
  const int wrow = wid >> 2, wcol = wid & 3;
  const int rr = lane & 15, kg = lane >> 4;
  const int sec = j0 >> 10;
  if (sec < 2) {
    const float* bias = sec ? bk : bq;
#pragma unroll
    for (int mi = 0; mi < 8; ++mi)
#pragma unroll
      for (int ni = 0; ni < 4; ++ni)
#pragma unroll
        for (int r = 0; r < 4; ++r) {
          int m = i0 + wrow * 128 + mi * 16 + kg * 4 + r;
          int n = j0 + wcol * 64 + ni * 16 + rr;
          int d = n & 1023;
          float v = acc[mi][ni][r] + bias[d];
          if (sec == 1) {
            int s = m & 2047;
            v += x[(size_t)m * 1024 + d] + P[(size_t)s * 1024 + d];
            Kpb[(size_t)m * 1024 + d] = f2b(v);
          } else {
            Qb[(size_t)m * 1024 + d] = f2b(v);
          }
        }
  } else {
    // V: transpose through (swizzled) LDS, then coalesced 16B stores
    u16* lt = lds;   // 256 x 256 bf16, col-major-ish: lt[d_local][s_local]
#pragma unroll
    for (int mi = 0; mi < 8; ++mi)
#pragma unroll
      for (int ni = 0; ni < 4; ++ni) {
        int cl = wcol * 64 + ni * 16 + rr;           // d_local
        int d = (j0 & 1023) + cl;
        float bvd = bv[d];
#pragma unroll
        for (int r = 0; r < 4; ++r) {
          int rl = wrow * 128 + mi * 16 + kg * 4 + r; // s_local
          lt[cl * 256 + (rl ^ ((cl & 7) << 3))] = f2b(acc[mi][ni][r] + bvd);
        }
      }
    __syncthreads();
    int b = i0 >> 11, s0 = i0 & 2047, d0 = j0 & 1023;
#pragma unroll
    for (int rnd = 0; rnd < 16; ++rnd) {
      int c = rnd * 512 + t;                  // 8192 x 16B chunks
      int drow = c >> 5, c16 = c & 31;
      int src = drow * 256 + ((c16 * 8) ^ ((drow & 7) << 3));
      *(u64x2*)(&Vtb[((size_t)b * 1024 + d0 + drow) * 2048 + s0 + c16 * 8]) =
          *(const u64x2*)(&lt[src]);
    }
  }
}

// ---------- kernel 2: scores (lower-triangular 256-tiles) ----------
__global__ __launch_bounds__(512, 2) void k_scores(
    const u16* __restrict__ Qb, const u16* __restrict__ Kpb,
    float* __restrict__ Sf)
{
  extern __shared__ __align__(16) u16 lds[];
  const int bx = blockIdx.x;
  const int b = bx / 36;
  const int tt = bx - b * 36;
  int bi = 0;
  while ((bi + 1) * (bi + 2) / 2 <= tt) ++bi;
  const int bj = tt - bi * (bi + 1) / 2;
  const int i0 = bi * 256, j0 = bj * 256;
  const u16* A = Qb + (size_t)b * 2048 * 1024;
  const u16* B = Kpb + (size_t)b * 2048 * 1024;

  f32x4 acc[8][4];
#pragma unroll
  for (int a = 0; a < 8; ++a)
#pragma unroll
    for (int c = 0; c < 4; ++c) acc[a][c] = (f32x4){0.f, 0.f, 0.f, 0.f};

  gemm256(A, 1024, B, 1024, i0, j0, 16, lds, acc);

  const int t = threadIdx.x, lane = t & 63, wid = t >> 6;
  const int wrow = wid >> 2, wcol = wid & 3;
  const int rr = lane & 15, kg = lane >> 4;
  float* Sb = Sf + (size_t)b * 2048 * 2048;
#pragma unroll
  for (int mi = 0; mi < 8; ++mi)
#pragma unroll
    for (int ni = 0; ni < 4; ++ni)
#pragma unroll
      for (int r = 0; r < 4; ++r) {
        int m = i0 + wrow * 128 + mi * 16 + kg * 4 + r;
        int n = j0 + wcol * 64 + ni * 16 + rr;
        Sb[(size_t)m * 2048 + n] = acc[mi][ni][r] * 0.03125f;
      }
}

// ---------- kernel 3: row softmax (causal), register-cached ----------
__global__ __launch_bounds__(256) void k_softmax(
    const float* __restrict__ Sf, u16* __restrict__ Pb)
{
  __shared__ float red[4];
  const int row = blockIdx.x;          // b*2048 + i
  const int i = row & 2047;
  const int L = i + 1;
  const int Jend = ((i >> 8) + 1) << 8;   // causal tile boundary for PV
  const float* s = Sf + (size_t)row * 2048;
  u16* p = Pb + (size_t)row * 2048;
  const int t = threadIdx.x;

  float vals[8];
  float m = -3.0e38f;
#pragma unroll
  for (int u = 0; u < 8; ++u) {
    int j = t + u * 256;
    if (j < L) { vals[u] = s[j]; m = fmaxf(m, vals[u]); }
  }
#pragma unroll
  for (int off = 32; off >= 1; off >>= 1) m = fmaxf(m, __shfl_down(m, off, 64));
  if ((t & 63) == 0) red[t >> 6] = m;
  __syncthreads();
  m = fmaxf(fmaxf(red[0], red[1]), fmaxf(red[2], red[3]));
  __syncthreads();

  float sum = 0.f;
#pragma unroll
  for (int u = 0; u < 8; ++u) {
    int j = t + u * 256;
    if (j < L) { vals[u] = __expf(vals[u] - m); sum += vals[u]; }
  }
#pragma unroll
  for (int off = 32; off >= 1; off >>= 1) sum += __shfl_down(sum, off, 64);
  if ((t & 63) == 0) red[t >> 6] = sum;
  __syncthreads();
  const float inv = 1.f / (red[0] + red[1] + red[2] + red[3]);

#pragma unroll
  for (int u = 0; u < 8; ++u) {
    int j = t + u * 256;
    if (j < Jend) p[j] = (j < L) ? f2b(vals[u] * inv) : (u16)0;
  }
}

// ---------- kernel 4: out = P @ V (pre-transposed Vtb) ----------
__global__ __launch_bounds__(512, 2) void k_pv(
    const u16* __restrict__ Pb, const u16* __restrict__ Vtb,
    float* __restrict__ out)
{
  extern __shared__ __align__(16) u16 lds[];
  const int bx = blockIdx.x;
  const int b = bx >> 5;
  const int bi = (bx >> 2) & 7;
  const int bj = bx & 3;
  const int i0 = bi * 256, j0 = bj * 256;
  const u16* A = Pb + (size_t)b * 2048 * 2048;   // lda 2048
  const u16* B = Vtb + (size_t)b * 1024 * 2048;  // ldb 2048

  f32x4 acc[8][4];
#pragma unroll
  for (int a = 0; a < 8; ++a)
#pragma unroll
    for (int c = 0; c < 4; ++c) acc[a][c] = (f32x4){0.f, 0.f, 0.f, 0.f};

  // causal: probs zero for j >= (bi+1)*256 -> only 4*(bi+1) K-tiles of 64
  gemm256(A, 2048, B, 2048, i0, j0, 4 * (bi + 1), lds, acc);

  const int t = threadIdx.x, lane = t & 63, wid = t >> 6;
  const int wrow = wid >> 2, wcol = wid & 3;
  const int rr = lane & 15, kg = lane >> 4;
  float* ob = out + (size_t)b * 2048 * 1024;
#pragma unroll
  for (int mi = 0; mi < 8; ++mi)
#pragma unroll
    for (int ni = 0; ni < 4; ++ni)
#pragma unroll
      for (int r = 0; r < 4; ++r) {
        int m = i0 + wrow * 128 + mi * 16 + kg * 4 + r;
        int n = j0 + wcol * 64 + ni * 16 + rr;
        ob[(size_t)m * 1024 + n] = acc[mi][ni][r];
      }
}

// ---------- launch ----------
extern "C" void kernel_launch(void* const* d_in, const int* in_sizes, int n_in,
                              void* d_out, int out_size, void* d_ws, size_t ws_size,
                              hipStream_t stream) {
  const float* x  = (const float*)d_in[0];
  const float* Wq = (const float*)d_in[1];
  const float* bq = (const float*)d_in[2];
  const float* Wk = (const float*)d_in[3];
  const float* bk = (const float*)d_in[4];
  const float* Wv = (const float*)d_in[5];
  const float* bv = (const float*)d_in[6];
  const float* P  = (const float*)d_in[7];
  float* out = (float*)d_out;

  char* w = (char*)d_ws;
  u16*  xb  = (u16*)(w);                   // 16 MB
  u16*  Wb  = (u16*)(w + (16ull << 20));   //  6 MB
  u16*  Qb  = (u16*)(w + (22ull << 20));   // 16 MB
  u16*  Kpb = (u16*)(w + (38ull << 20));   // 16 MB
  u16*  Vtb = (u16*)(w + (54ull << 20));   // 16 MB
  float* Sf = (float*)(w + (70ull << 20)); // 64 MB
  u16*  Pb  = (u16*)(w + (134ull << 20));  // 32 MB

  const int LDSB = 131072;
  (void)hipFuncSetAttribute((const void*)k_qkv,
        hipFuncAttributeMaxDynamicSharedMemorySize, LDSB);
  (void)hipFuncSetAttribute((const void*)k_scores,
        hipFuncAttributeMaxDynamicSharedMemorySize, LDSB);
  (void)hipFuncSetAttribute((const void*)k_pv,
        hipFuncAttributeMaxDynamicSharedMemorySize, LDSB);

  hipLaunchKernelGGL(k_convert, dim3(11264), dim3(256), 0, stream,
                     x, Wq, Wk, Wv, xb, Wb);
  hipLaunchKernelGGL(k_qkv, dim3(384), dim3(512), LDSB, stream,
                     xb, Wb, bq, bk, bv, x, P, Qb, Kpb, Vtb);
  hipLaunchKernelGGL(k_scores, dim3(144), dim3(512), LDSB, stream,
                     Qb, Kpb, Sf);
  hipLaunchKernelGGL(k_softmax, dim3(8192), dim3(256), 0, stream,
                     Sf, Pb);
  hipLaunchKernelGGL(k_pv, dim3(128), dim3(512), LDSB, stream,
                     Pb, Vtb, out);
}